// Round 1
// baseline (1296.910 us; speedup 1.0000x reference)
//
#include <hip/hip_runtime.h>

typedef unsigned short u16;
typedef unsigned int u32;

#define N_ATOMS 100000
#define N_BONDS 200000
#define N_EDGES 100000
#define HIDDEN 300
#define HP 320
#define ATOM_FDIM 133
#define BOND_FDIM 147
#define BFP 160
#define CATD 433
#define CATP 448
#define N_MOLS 2000

typedef __bf16 bf16x8 __attribute__((ext_vector_type(8)));
typedef float f32x4 __attribute__((ext_vector_type(4)));

__device__ __forceinline__ u16 f2bf(float f) {
    union { float f; u32 u; } x; x.f = f;
    u32 u = x.u;
    u32 r = u + 0x7fffu + ((u >> 16) & 1u);
    return (u16)(r >> 16);
}
__device__ __forceinline__ float bf2f(u16 h) {
    union { u32 u; float f; } x; x.u = ((u32)h) << 16;
    return x.f;
}

union U8 { uint4 v; u16 h[8]; };

// ---------------- generic bf16 MFMA GEMM ----------------
// C[M,N] = A[M,K] @ B[K,N], A row-major bf16 (lda), B given transposed Bt[N][K] bf16 (ldb=K stride).
// MODE 0: Cf[grow*ldc+gcol] = acc + bias[gcol]            (gcol < Nout)
// MODE 1: O2 = bf16(acc); O1 = bf16(relu(acc))            (stride HP)
// MODE 2: O1 = bf16(relu(acc + bf2f(inp_in)))             (stride HP)
// MODE 3: O1 = bf16(relu(acc + (gcol<Nout?bias:0)))       (stride HP)
template<int MODE>
__global__ __launch_bounds__(256) void k_gemm(
    const u16* __restrict__ A, int lda, int M,
    const u16* __restrict__ Bt, int ldb, int K,
    int Nout, float* __restrict__ Cf, int ldc,
    const float* __restrict__ bias,
    u16* __restrict__ O1, u16* __restrict__ O2,
    const u16* __restrict__ inp_in)
{
    __shared__ __align__(16) u16 As[128 * 40];
    __shared__ __align__(16) u16 Bs[64 * 40];

    const int tid = threadIdx.x;
    const int row0 = blockIdx.x * 128;
    const int n0 = blockIdx.y * 64;
    const int lane = tid & 63;
    const int w = tid >> 6, wr = w >> 1, wc = w & 1;
    const int lrow = lane & 15, lkb = (lane >> 4) * 8;

    // staging: A = 512 chunks of 16B (128 rows x 4 kgroups), B = 256 chunks
    const int rA0 = tid >> 2, kg = tid & 3;
    const int rA1 = (tid + 256) >> 2;
    const int rB = tid >> 2;

    int gA0 = row0 + rA0; if (gA0 >= M) gA0 = M - 1;
    int gA1 = row0 + rA1; if (gA1 >= M) gA1 = M - 1;

    const u16* pa0 = A + (size_t)gA0 * lda + kg * 8;
    const u16* pa1 = A + (size_t)gA1 * lda + kg * 8;
    const u16* pb  = Bt + (size_t)(n0 + rB) * ldb + kg * 8;

    uint4 va0 = *(const uint4*)pa0;
    uint4 va1 = *(const uint4*)pa1;
    uint4 vb  = *(const uint4*)pb;

    f32x4 acc[4][2] = {};

    for (int k0 = 0; k0 < K; k0 += 32) {
        *(uint4*)&As[rA0 * 40 + kg * 8] = va0;
        *(uint4*)&As[rA1 * 40 + kg * 8] = va1;
        *(uint4*)&Bs[rB  * 40 + kg * 8] = vb;
        __syncthreads();
        if (k0 + 32 < K) {
            va0 = *(const uint4*)(pa0 + k0 + 32);
            va1 = *(const uint4*)(pa1 + k0 + 32);
            vb  = *(const uint4*)(pb  + k0 + 32);
        }
        bf16x8 af[4], bfr[2];
#pragma unroll
        for (int m = 0; m < 4; m++)
            af[m] = *(const bf16x8*)&As[(wr * 64 + m * 16 + lrow) * 40 + lkb];
#pragma unroll
        for (int n = 0; n < 2; n++)
            bfr[n] = *(const bf16x8*)&Bs[(wc * 32 + n * 16 + lrow) * 40 + lkb];
#pragma unroll
        for (int m = 0; m < 4; m++)
#pragma unroll
            for (int n = 0; n < 2; n++)
                acc[m][n] = __builtin_amdgcn_mfma_f32_16x16x32_bf16(af[m], bfr[n], acc[m][n], 0, 0, 0);
        __syncthreads();
    }

    const int orow = (lane >> 4) * 4;
    const int ocol = lane & 15;
#pragma unroll
    for (int m = 0; m < 4; m++) {
#pragma unroll
        for (int n = 0; n < 2; n++) {
#pragma unroll
            for (int r = 0; r < 4; r++) {
                int grow = row0 + wr * 64 + m * 16 + orow + r;
                int gcol = n0 + wc * 32 + n * 16 + ocol;
                float v = acc[m][n][r];
                if (MODE == 0) {
                    if (grow < M && gcol < Nout)
                        Cf[(size_t)grow * ldc + gcol] = v + bias[gcol];
                } else if (MODE == 1) {
                    if (grow < M) {
                        O2[(size_t)grow * HP + gcol] = f2bf(v);
                        O1[(size_t)grow * HP + gcol] = f2bf(fmaxf(v, 0.f));
                    }
                } else if (MODE == 2) {
                    if (grow < M) {
                        float x = v + bf2f(inp_in[(size_t)grow * HP + gcol]);
                        O1[(size_t)grow * HP + gcol] = f2bf(fmaxf(x, 0.f));
                    }
                } else {
                    if (grow < M) {
                        float x = v + (gcol < Nout ? bias[gcol] : 0.f);
                        O1[(size_t)grow * HP + gcol] = f2bf(fmaxf(x, 0.f));
                    }
                }
            }
        }
    }
}

// ---------------- weight pack: Bt[n][k] = W[k][n], bf16, zero-padded ----------------
__global__ void k_pack_wt(const float* __restrict__ W, u16* __restrict__ Bt,
                          int K, int N, int Kp, int Np)
{
    int idx = blockIdx.x * 256 + threadIdx.x;
    if (idx >= Np * Kp) return;
    int n = idx / Kp, k = idx - n * Kp;
    Bt[idx] = (n < N && k < K) ? f2bf(W[(size_t)k * N + n]) : (u16)0;
}

// ---------------- f_bonds fp32 [B][147] -> bf16 [B][160] ----------------
__global__ void k_pack_bonds(const float* __restrict__ fb, u16* __restrict__ out)
{
    int idx = blockIdx.x * 256 + threadIdx.x;
    if (idx >= N_BONDS * BFP) return;
    int b = idx / BFP, c = idx - b * BFP;
    out[idx] = (c < BOND_FDIM) ? f2bf(fb[(size_t)b * BOND_FDIM + c]) : (u16)0;
}

// ---------------- a_msg[a] = sum_j msg[a2b[a][j]] ----------------
__global__ __launch_bounds__(256) void k_aggregate(const u16* __restrict__ msg,
    const int* __restrict__ a2b, u16* __restrict__ amsg)
{
    int idx = blockIdx.x * 256 + threadIdx.x;
    if (idx >= N_ATOMS * 40) return;
    int a = idx / 40, c = (idx - a * 40) * 8;
    float s[8] = {};
#pragma unroll
    for (int j = 0; j < 6; j++) {
        int b = a2b[a * 6 + j];
        U8 u; u.v = *(const uint4*)&msg[(size_t)b * HP + c];
#pragma unroll
        for (int i = 0; i < 8; i++) s[i] += bf2f(u.h[i]);
    }
    U8 o;
#pragma unroll
    for (int i = 0; i < 8; i++) o.h[i] = f2bf(s[i]);
    *(uint4*)&amsg[(size_t)a * HP + c] = o.v;
}

// ---------------- delta[b] = a_msg[b2a[b]] - msg[b2revb[b]] ----------------
__global__ __launch_bounds__(256) void k_delta(const u16* __restrict__ amsg,
    const u16* __restrict__ msg, const int* __restrict__ b2a,
    const int* __restrict__ b2revb, u16* __restrict__ dlt)
{
    int idx = blockIdx.x * 256 + threadIdx.x;
    if (idx >= N_BONDS * 40) return;
    int b = idx / 40, c = (idx - b * 40) * 8;
    int src = b2a[b];
    int rb = b2revb[b];
    U8 ua; ua.v = *(const uint4*)&amsg[(size_t)src * HP + c];
    U8 um; um.v = *(const uint4*)&msg[(size_t)rb * HP + c];
    U8 o;
#pragma unroll
    for (int i = 0; i < 8; i++) o.h[i] = f2bf(bf2f(ua.h[i]) - bf2f(um.h[i]));
    *(uint4*)&dlt[(size_t)b * HP + c] = o.v;
}

// ---------------- cat[r] = [f_atoms[r] (133) | a_msg[r] (300) | 0 pad] ----------------
__global__ void k_cat(const float* __restrict__ fa, const u16* __restrict__ amsg,
                      u16* __restrict__ cat)
{
    int idx = blockIdx.x * 256 + threadIdx.x;
    if (idx >= N_ATOMS * CATP) return;
    int r = idx / CATP, c = idx - r * CATP;
    u16 v;
    if (c < ATOM_FDIM) v = f2bf(fa[(size_t)r * ATOM_FDIM + c]);
    else if (c < CATD) v = amsg[(size_t)r * HP + (c - ATOM_FDIM)];
    else v = 0;
    cat[idx] = v;
}

// ---------------- h_avg[e] = 0.5*(ah[b2a[2e]] + ah[b2a[b2revb[2e]]]) ----------------
__global__ __launch_bounds__(256) void k_havg(const u16* __restrict__ ah,
    const int* __restrict__ b2a, const int* __restrict__ b2revb,
    u16* __restrict__ hv)
{
    int idx = blockIdx.x * 256 + threadIdx.x;
    if (idx >= N_EDGES * 40) return;
    int e = idx / 40, c = (idx - e * 40) * 8;
    int e1 = 2 * e;
    int a1 = b2a[e1];
    int a2 = b2a[b2revb[e1]];
    U8 u1; u1.v = *(const uint4*)&ah[(size_t)a1 * HP + c];
    U8 u2; u2.v = *(const uint4*)&ah[(size_t)a2 * HP + c];
    U8 o;
#pragma unroll
    for (int i = 0; i < 8; i++) o.h[i] = f2bf(0.5f * (bf2f(u1.h[i]) + bf2f(u2.h[i])));
    *(uint4*)&hv[(size_t)e * HP + c] = o.v;
}

// ---------------- per-molecule segment sum (graph_idx sorted) ----------------
__device__ __forceinline__ int lower_bound_i(const int* a, int n, int v) {
    int lo = 0, hi = n;
    while (lo < hi) { int mid = (lo + hi) >> 1; if (a[mid] < v) lo = mid + 1; else hi = mid; }
    return lo;
}
__global__ __launch_bounds__(320) void k_segsum(const u16* __restrict__ ah,
    const int* __restrict__ gidx, float* __restrict__ gemb)
{
    int g = blockIdx.x;
    int c = threadIdx.x;
    int s = lower_bound_i(gidx, N_ATOMS, g);
    int e = lower_bound_i(gidx, N_ATOMS, g + 1);
    float sum = 0.f;
    for (int a = s; a < e; a++) sum += bf2f(ah[(size_t)a * HP + c]);
    gemb[(size_t)g * HP + c] = sum;
}

// ---------------- graph head (fp32) ----------------
__global__ __launch_bounds__(320) void k_g1(const float* __restrict__ gemb,
    const float* __restrict__ W, const float* __restrict__ b, float* __restrict__ gh)
{
    int g = blockIdx.x, j = threadIdx.x;
    float acc = 0.f;
    if (j < HIDDEN) {
        acc = b[j];
        for (int k = 0; k < HIDDEN; k++)
            acc = fmaf(gemb[(size_t)g * HP + k], W[(size_t)k * HIDDEN + j], acc);
        acc = fmaxf(acc, 0.f);
    }
    gh[(size_t)g * HP + j] = (j < HIDDEN) ? acc : 0.f;
}
__global__ __launch_bounds__(64) void k_g2(const float* __restrict__ gh,
    const float* __restrict__ W, const float* __restrict__ b, float* __restrict__ out)
{
    int g = blockIdx.x, l = threadIdx.x;
    float acc = 0.f;
    for (int j = l; j < HIDDEN; j += 64) acc += gh[(size_t)g * HP + j] * W[j];
#pragma unroll
    for (int off = 32; off; off >>= 1) acc += __shfl_down(acc, off, 64);
    if (l == 0) out[g] = acc + b[0];
}

extern "C" void kernel_launch(void* const* d_in, const int* in_sizes, int n_in,
                              void* d_out, int out_size, void* d_ws, size_t ws_size,
                              hipStream_t stream)
{
    const float* f_atoms = (const float*)d_in[0];
    const float* f_bonds = (const float*)d_in[1];
    const int* a2b    = (const int*)d_in[2];
    const int* b2a    = (const int*)d_in[3];
    const int* b2revb = (const int*)d_in[4];
    const int* gidx   = (const int*)d_in[5];
    const float* W_i    = (const float*)d_in[6];
    const float* W_h    = (const float*)d_in[7];
    const float* W_o    = (const float*)d_in[8];
    const float* b_o    = (const float*)d_in[9];
    const float* W_node = (const float*)d_in[10];
    const float* b_node = (const float*)d_in[11];
    const float* W_edge = (const float*)d_in[12];
    const float* b_edge = (const float*)d_in[13];
    const float* W_g1   = (const float*)d_in[14];
    const float* b_g1   = (const float*)d_in[15];
    const float* W_g2   = (const float*)d_in[16];
    const float* b_g2   = (const float*)d_in[17];

    char* ws = (char*)d_ws;
    u16* inp  = (u16*)(ws + 0);            // 128 MB; reused as ah after loop
    u16* msg  = (u16*)(ws + 128000000);    // 128 MB; reused as h_avg
    u16* reg2 = (u16*)(ws + 256000000);    // 128 MB; fbonds_bf16 -> delta -> cat
    u16* amsg = (u16*)(ws + 384000000);    // 64 MB
    u16* wt_i = (u16*)(ws + 448000000);    // 320x160
    u16* wt_h = (u16*)(ws + 448200000);    // 320x320
    u16* wt_o = (u16*)(ws + 448500000);    // 320x448
    u16* wt_n = (u16*)(ws + 448800000);    // 192x320
    u16* wt_e = (u16*)(ws + 448950000);    // 64x320
    float* gemb = (float*)(ws + 449000000); // 2000x320 f32
    float* gh   = (float*)(ws + 452000000); // 2000x320 f32

    float* out_node  = (float*)d_out;
    float* out_edge  = out_node + (size_t)N_ATOMS * ATOM_FDIM;     // +13,300,000
    float* out_graph = out_node + 14700000;

    dim3 blk(256);

    // pack weights (bf16, transposed, padded)
    k_pack_wt<<<(320 * 160 + 255) / 256, blk, 0, stream>>>(W_i, wt_i, BOND_FDIM, HIDDEN, 160, 320);
    k_pack_wt<<<(320 * 320 + 255) / 256, blk, 0, stream>>>(W_h, wt_h, HIDDEN, HIDDEN, 320, 320);
    k_pack_wt<<<(320 * 448 + 255) / 256, blk, 0, stream>>>(W_o, wt_o, CATD, HIDDEN, 448, 320);
    k_pack_wt<<<(192 * 320 + 255) / 256, blk, 0, stream>>>(W_node, wt_n, HIDDEN, ATOM_FDIM, 320, 192);
    k_pack_wt<<<(64 * 320 + 255) / 256, blk, 0, stream>>>(W_edge, wt_e, HIDDEN, 14, 320, 64);

    // pack bonds into reg2
    k_pack_bonds<<<(N_BONDS * BFP + 255) / 256, blk, 0, stream>>>(f_bonds, reg2);

    // inp = f_bonds @ W_i ; msg = relu(inp)
    k_gemm<1><<<dim3(1563, 5), blk, 0, stream>>>(reg2, BFP, N_BONDS, wt_i, BFP, BFP,
        0, nullptr, 0, nullptr, msg, inp, nullptr);

    // depth loop (DEPTH-1 = 2)
    for (int d = 0; d < 2; ++d) {
        k_aggregate<<<(N_ATOMS * 40 + 255) / 256, blk, 0, stream>>>(msg, a2b, amsg);
        k_delta<<<(N_BONDS * 40 + 255) / 256, blk, 0, stream>>>(amsg, msg, b2a, b2revb, reg2);
        k_gemm<2><<<dim3(1563, 5), blk, 0, stream>>>(reg2, HP, N_BONDS, wt_h, HP, HP,
            0, nullptr, 0, nullptr, msg, nullptr, inp);
    }

    // final aggregate + concat + W_o
    k_aggregate<<<(N_ATOMS * 40 + 255) / 256, blk, 0, stream>>>(msg, a2b, amsg);
    k_cat<<<(N_ATOMS * CATP + 255) / 256, blk, 0, stream>>>(f_atoms, amsg, reg2);
    u16* ah = inp; // reuse
    k_gemm<3><<<dim3(782, 5), blk, 0, stream>>>(reg2, CATP, N_ATOMS, wt_o, CATP, CATP,
        HIDDEN, nullptr, 0, b_o, ah, nullptr, nullptr);

    // node head
    k_gemm<0><<<dim3(782, 3), blk, 0, stream>>>(ah, HP, N_ATOMS, wt_n, HP, HP,
        ATOM_FDIM, out_node, ATOM_FDIM, b_node, nullptr, nullptr, nullptr);

    // edge head
    u16* hv = msg; // reuse
    k_havg<<<(N_EDGES * 40 + 255) / 256, blk, 0, stream>>>(ah, b2a, b2revb, hv);
    k_gemm<0><<<dim3(782, 1), blk, 0, stream>>>(hv, HP, N_EDGES, wt_e, HP, HP,
        14, out_edge, 14, b_edge, nullptr, nullptr, nullptr);

    // graph head
    k_segsum<<<N_MOLS, 320, 0, stream>>>(ah, gidx, gemb);
    k_g1<<<N_MOLS, 320, 0, stream>>>(gemb, W_g1, b_g1, gh);
    k_g2<<<N_MOLS, 64, 0, stream>>>(gh, W_g2, b_g2, out_graph);
}